// Round 2
// baseline (178.907 us; speedup 1.0000x reference)
//
#include <hip/hip_runtime.h>
#include <math.h>

// ---------------------------------------------------------------------------
// Reference takes _lstm4(...)[0] -> only t=0 matters; h0=c0=0 makes every
// layer feed-forward: z = x0 @ Wih^T + b, c = sig(i)*tanh(g), out =
// tanh(sig(o)*tanh(c)).
//
// R5: two dispatches (prep + fused), SLICED big layers. The fused kernel's
// floor was the per-CU L2 weight stream (each block read all 840KB weights
// ~= 5.8us). Now: 256 blocks = 64 row-groups x 4 slices. Phase1: block
// (g,s) computes h1[j in 64s..64s+64) for rows 4g..4g+3 (reads W1/4 = 67KB).
// Phase2: same for h2 slice (W2/4 = 98KB). Tail: block handles row 4g+s
// alone (180KB). Weight bytes/block: 840 -> 344KB. Cross-block handoff of
// h1/h2 via agent-scope atomics + 4-block flag barriers (flags zeroed by
// prep each iteration; 256 blocks on 256 CUs are always co-resident).
// ---------------------------------------------------------------------------

// ws layout (float offsets). Transposed weights k-major, f-gate dropped,
// packed gate order i | g | o (same as proven R3 prep).
#define O_W1T 0        // 87  x 768
#define O_W2T 66816    // 256 x 384
#define O_W3T 165120   // 128 x 192
#define O_W4T 189696   // 64  x 96
#define O_F1T 195840   // 32  x 128
#define O_F2T 199936   // 128 x 64
#define O_F3T 208128   // 64  x 32
#define O_B1  210176   // 768
#define O_B2  210944   // 384
#define O_B3  211328   // 192
#define O_B4  211520   // 96
#define O_FLG 211616   // 128 ints (64 groups x 2 barriers)
#define O_H1  211744   // 256 x 256 h1 staging
#define O_H2  277280   // 256 x 128 h2 staging

__global__ __launch_bounds__(256) void prep_kernel(
    const float* __restrict__ w1i, const float* __restrict__ w2i,
    const float* __restrict__ w3i, const float* __restrict__ w4i,
    const float* __restrict__ b1,  const float* __restrict__ b2,
    const float* __restrict__ b3,  const float* __restrict__ b4,
    const float* __restrict__ f1w, const float* __restrict__ f2w,
    const float* __restrict__ f3w, float* __restrict__ ws)
{
    int i = blockIdx.x * 256 + threadIdx.x;
    if (i < 128) ((int*)ws)[O_FLG + i] = 0;            // zero barrier flags
    if (i < 89088) {                                   // w1i [1024 x 87], H=256
        int row = i / 87, k = i - row * 87;
        int g = row >> 8;
        if (g != 1) {
            int base = (g == 0) ? 0 : (g == 2) ? 256 : 512;
            ws[O_W1T + k * 768 + base + (row & 255)] = w1i[i];
        }
    } else if (i < 220160) {                           // w2i [512 x 256], H=128
        int l = i - 89088;
        int row = l >> 8, k = l & 255;
        int g = row >> 7;
        if (g != 1) {
            int base = (g == 0) ? 0 : (g == 2) ? 128 : 256;
            ws[O_W2T + k * 384 + base + (row & 127)] = w2i[l];
        }
    } else if (i < 252928) {                           // w3i [256 x 128], H=64
        int l = i - 220160;
        int row = l >> 7, k = l & 127;
        int g = row >> 6;
        if (g != 1) {
            int base = (g == 0) ? 0 : (g == 2) ? 64 : 128;
            ws[O_W3T + k * 192 + base + (row & 63)] = w3i[l];
        }
    } else if (i < 261120) {                           // w4i [128 x 64], H=32
        int l = i - 252928;
        int row = l >> 6, k = l & 63;
        int g = row >> 5;
        if (g != 1) {
            int base = (g == 0) ? 0 : (g == 2) ? 32 : 64;
            ws[O_W4T + k * 96 + base + (row & 31)] = w4i[l];
        }
    } else if (i < 262144) {                           // b1 [1024]
        int l = i - 261120;
        int g = l >> 8;
        if (g != 1) {
            int base = (g == 0) ? 0 : (g == 2) ? 256 : 512;
            ws[O_B1 + base + (l & 255)] = b1[l];
        }
    } else if (i < 262656) {                           // b2 [512]
        int l = i - 262144;
        int g = l >> 7;
        if (g != 1) {
            int base = (g == 0) ? 0 : (g == 2) ? 128 : 256;
            ws[O_B2 + base + (l & 127)] = b2[l];
        }
    } else if (i < 262912) {                           // b3 [256]
        int l = i - 262656;
        int g = l >> 6;
        if (g != 1) {
            int base = (g == 0) ? 0 : (g == 2) ? 64 : 128;
            ws[O_B3 + base + (l & 63)] = b3[l];
        }
    } else if (i < 263040) {                           // b4 [128]
        int l = i - 262912;
        int g = l >> 5;
        if (g != 1) {
            int base = (g == 0) ? 0 : (g == 2) ? 32 : 64;
            ws[O_B4 + base + (l & 31)] = b4[l];
        }
    } else if (i < 267136) {                           // f1w [128 x 32]
        int l = i - 263040;
        int j = l >> 5, k = l & 31;
        ws[O_F1T + k * 128 + j] = f1w[l];
    } else if (i < 275328) {                           // f2w [64 x 128]
        int l = i - 267136;
        int j = l >> 7, k = l & 127;
        ws[O_F2T + k * 64 + j] = f2w[l];
    } else if (i < 277376) {                           // f3w [32 x 64]
        int l = i - 275328;
        int j = l >> 6, k = l & 63;
        ws[O_F3T + k * 32 + j] = f3w[l];
    }
}

__device__ __forceinline__ float frcp(float x) { return __builtin_amdgcn_rcpf(x); }
__device__ __forceinline__ float sigm(float x) { return frcp(1.0f + __expf(-x)); }
__device__ __forceinline__ float tanh_f(float x) { return 1.0f - 2.0f * frcp(1.0f + __expf(2.0f * x)); }
__device__ __forceinline__ float cell(float zi, float zg, float zo) {
    float c = sigm(zi) * tanh_f(zg);
    return tanh_f(sigm(zo) * tanh_f(c));
}

#define FMA4(z, xv, wv) \
    z.x = fmaf(xv, wv.x, z.x); z.y = fmaf(xv, wv.y, z.y); \
    z.z = fmaf(xv, wv.z, z.z); z.w = fmaf(xv, wv.w, z.w);

__global__ __launch_bounds__(512) void lstm_fused_sliced(
    const float* __restrict__ x, float* __restrict__ ws,
    const float* __restrict__ f1b, const float* __restrict__ f2b,
    const float* __restrict__ f3b, const float* __restrict__ f4w,
    const float* __restrict__ f4b, float* __restrict__ out)
{
    const int t = threadIdx.x;
    const int g = blockIdx.x >> 2;            // row group (4 rows)
    const int s = blockIdx.x & 3;             // output slice
    const int row = blockIdx.x;               // tail row = 4g+s

    __shared__ __align__(16) float xs4[348];
    __shared__ __align__(16) float buf[1536];
    __shared__ __align__(16) float hbuf[1024];
    __shared__ float h3s[64], h4s[32], a1s[128], a2s[64], a3s[32];

    const float* W1T = ws + O_W1T;
    const float* W2T = ws + O_W2T;
    const float* W3T = ws + O_W3T;
    const float* W4T = ws + O_W4T;
    const float* F1T = ws + O_F1T;
    const float* F2T = ws + O_F2T;
    const float* F3T = ws + O_F3T;
    int* flg1 = (int*)ws + O_FLG + g;
    int* flg2 = (int*)ws + O_FLG + 64 + g;

    // x rows 4g..4g+3 (contiguous 348 floats of the t=0 slab)
    if (t < 348) xs4[t] = x[g * 348 + t];

    // bias preloads (issue early; consumed after combine barriers)
    float b1i = 0.f, b1g = 0.f, b1o = 0.f;
    float b2i = 0.f, b2g = 0.f, b2o = 0.f;
    float b3i = 0.f, b3g = 0.f, b3o = 0.f;
    float b4i = 0.f, b4g = 0.f, b4o = 0.f;
    float vf1 = 0.f, vf2 = 0.f, vf3 = 0.f;
    {
        const float* B1p = ws + O_B1;
        const float* B2p = ws + O_B2;
        const float* B3p = ws + O_B3;
        const float* B4p = ws + O_B4;
        int j6 = t & 63, j5 = t & 31;
        if (t < 256) { b1i = B1p[s*64+j6]; b1g = B1p[256+s*64+j6]; b1o = B1p[512+s*64+j6]; }
        if (t < 128) { b2i = B2p[s*32+j5]; b2g = B2p[128+s*32+j5]; b2o = B2p[256+s*32+j5]; vf1 = f1b[t]; }
        if (t < 64)  { b3i = B3p[t]; b3g = B3p[64+t]; b3o = B3p[128+t]; vf2 = f2b[t]; }
        if (t < 32)  { b4i = B4p[t]; b4g = B4p[32+t]; b4o = B4p[64+t]; vf3 = f3b[t]; }
    }
    __syncthreads();

    // ================= Phase 1: h1 slice (87 -> 256), W1/4 = 67KB =========
    // tasks (kappa 2, r 4, gate 3, q 16) = 384 threads, float4 col quads
    if (t < 384) {
        const int kk = t / 192;
        const int u  = t - kk * 192;
        const int r  = u / 48;
        const int v  = u - r * 48;
        const int gate = v >> 4, q = v & 15;
        const int col = gate * 256 + s * 64 + q * 4;
        const float* wp = W1T + col;
        const float* xr = xs4 + r * 87;
        const int k0 = kk ? 44 : 0, k1 = kk ? 87 : 44;
        float4 z = {0.f, 0.f, 0.f, 0.f};
        #pragma unroll 4
        for (int k = k0; k < k1; ++k) {
            const float4 wv = *(const float4*)(wp + k * 768);
            const float xv = xr[k];
            FMA4(z, xv, wv);
        }
        *(float4*)&buf[kk * 768 + r * 192 + gate * 64 + q * 4] = z;
    }
    __syncthreads();
    if (t < 256) {
        const int r = t >> 6, j = t & 63;
        const float zi = buf[r*192 + j]       + buf[768 + r*192 + j]       + b1i;
        const float zg = buf[r*192 + 64 + j]  + buf[768 + r*192 + 64 + j]  + b1g;
        const float zo = buf[r*192 + 128 + j] + buf[768 + r*192 + 128 + j] + b1o;
        const float h = cell(zi, zg, zo);
        __hip_atomic_store(&ws[O_H1 + (4*g + r) * 256 + s * 64 + j], h,
                           __ATOMIC_RELAXED, __HIP_MEMORY_SCOPE_AGENT);
    }
    __syncthreads();                           // drains vmcnt before arrive
    if (t == 0)
        __hip_atomic_fetch_add(flg1, 1, __ATOMIC_RELEASE, __HIP_MEMORY_SCOPE_AGENT);

    // ---- barrier 1: wait for all 4 slices of this row group ----
    if (t == 0) {
        while (__hip_atomic_load(flg1, __ATOMIC_RELAXED, __HIP_MEMORY_SCOPE_AGENT) < 4)
            __builtin_amdgcn_s_sleep(2);
        (void)__hip_atomic_load(flg1, __ATOMIC_ACQUIRE, __HIP_MEMORY_SCOPE_AGENT);
    }
    __syncthreads();
    for (int i = t; i < 1024; i += 512)
        hbuf[i] = __hip_atomic_load(&ws[O_H1 + g * 1024 + i],
                                    __ATOMIC_RELAXED, __HIP_MEMORY_SCOPE_AGENT);
    __syncthreads();

    // ================= Phase 2: h2 slice (256 -> 128), W2/4 = 98KB ========
    // tasks (kappa 4, r 4, gate 3, q 8) = 384 threads
    if (t < 384) {
        const int kk = t / 96;
        const int u  = t - kk * 96;
        const int r  = u / 24;
        const int v  = u - r * 24;
        const int gate = v >> 3, q = v & 7;
        const int col = gate * 128 + s * 32 + q * 4;
        const float* wp = W2T + col;
        const float* hr = hbuf + r * 256;
        const int k0 = kk * 64;
        float4 z = {0.f, 0.f, 0.f, 0.f};
        #pragma unroll 4
        for (int k = k0; k < k0 + 64; ++k) {
            const float4 wv = *(const float4*)(wp + k * 384);
            const float hv = hr[k];
            FMA4(z, hv, wv);
        }
        *(float4*)&buf[kk * 384 + r * 96 + gate * 32 + q * 4] = z;
    }
    __syncthreads();
    if (t < 128) {
        const int r = t >> 5, j = t & 31;
        float zi = b2i, zg = b2g, zo = b2o;
        #pragma unroll
        for (int kk = 0; kk < 4; ++kk) {
            zi += buf[kk*384 + r*96 + j];
            zg += buf[kk*384 + r*96 + 32 + j];
            zo += buf[kk*384 + r*96 + 64 + j];
        }
        const float h = cell(zi, zg, zo);
        __hip_atomic_store(&ws[O_H2 + (4*g + r) * 128 + s * 32 + j], h,
                           __ATOMIC_RELAXED, __HIP_MEMORY_SCOPE_AGENT);
    }
    __syncthreads();
    if (t == 0)
        __hip_atomic_fetch_add(flg2, 1, __ATOMIC_RELEASE, __HIP_MEMORY_SCOPE_AGENT);

    // ---- barrier 2 ----
    if (t == 0) {
        while (__hip_atomic_load(flg2, __ATOMIC_RELAXED, __HIP_MEMORY_SCOPE_AGENT) < 4)
            __builtin_amdgcn_s_sleep(2);
        (void)__hip_atomic_load(flg2, __ATOMIC_ACQUIRE, __HIP_MEMORY_SCOPE_AGENT);
    }
    __syncthreads();
    if (t < 128)
        hbuf[t] = __hip_atomic_load(&ws[O_H2 + row * 128 + t],
                                    __ATOMIC_RELAXED, __HIP_MEMORY_SCOPE_AGENT);
    __syncthreads();

    // ================= Tail: this block alone handles row 4g+s ============
    // ---- LSTM3: 128 -> 64, 192 cols (i|g|o), K=128. (kappa 8, Q 48) ----
    if (t < 384) {
        const int kk = t / 48, Q = t - kk * 48;
        const float* wp = W3T + 4 * Q;
        const int k0 = kk * 16;
        float4 z = {0.f, 0.f, 0.f, 0.f};
        #pragma unroll
        for (int k = k0; k < k0 + 16; ++k) {
            const float4 wv = *(const float4*)(wp + k * 192);
            const float hv = hbuf[k];
            FMA4(z, hv, wv);
        }
        *(float4*)&buf[kk * 192 + 4 * Q] = z;
    }
    __syncthreads();
    if (t < 64) {
        float zi = b3i, zg = b3g, zo = b3o;
        #pragma unroll
        for (int kk = 0; kk < 8; ++kk) {
            zi += buf[kk*192 + t];
            zg += buf[kk*192 + 64 + t];
            zo += buf[kk*192 + 128 + t];
        }
        h3s[t] = cell(zi, zg, zo);
    }
    __syncthreads();

    // ---- LSTM4: 64 -> 32, 96 cols, K=64. (kappa 16, Q 24) ----
    if (t < 384) {
        const int kk = t / 24, Q = t - kk * 24;
        const float* wp = W4T + 4 * Q;
        const int k0 = kk * 4;
        float4 z = {0.f, 0.f, 0.f, 0.f};
        #pragma unroll
        for (int k = k0; k < k0 + 4; ++k) {
            const float4 wv = *(const float4*)(wp + k * 96);
            const float hv = h3s[k];
            FMA4(z, hv, wv);
        }
        *(float4*)&buf[kk * 96 + 4 * Q] = z;
    }
    __syncthreads();
    if (t < 32) {
        float zi = b4i, zg = b4g, zo = b4o;
        #pragma unroll
        for (int kk = 0; kk < 16; ++kk) {
            zi += buf[kk*96 + t];
            zg += buf[kk*96 + 32 + t];
            zo += buf[kk*96 + 64 + t];
        }
        h4s[t] = cell(zi, zg, zo);
    }
    __syncthreads();

    // ---- FC1: 32 -> 128, relu. (kappa 8, Q 32) ----
    if (t < 256) {
        const int kk = t >> 5, Q = t & 31;
        const float* wp = F1T + 4 * Q;
        const int k0 = kk * 4;
        float4 z = {0.f, 0.f, 0.f, 0.f};
        #pragma unroll
        for (int k = k0; k < k0 + 4; ++k) {
            const float4 wv = *(const float4*)(wp + k * 128);
            const float hv = h4s[k];
            FMA4(z, hv, wv);
        }
        *(float4*)&buf[kk * 128 + 4 * Q] = z;
    }
    __syncthreads();
    if (t < 128) {
        float a = vf1;
        #pragma unroll
        for (int kk = 0; kk < 8; ++kk) a += buf[kk*128 + t];
        a1s[t] = fmaxf(a, 0.0f);
    }
    __syncthreads();

    // ---- FC2: 128 -> 64, relu. (kappa 16, Q 16) ----
    if (t < 256) {
        const int kk = t >> 4, Q = t & 15;
        const float* wp = F2T + 4 * Q;
        const int k0 = kk * 8;
        float4 z = {0.f, 0.f, 0.f, 0.f};
        #pragma unroll
        for (int k = k0; k < k0 + 8; ++k) {
            const float4 wv = *(const float4*)(wp + k * 64);
            const float hv = a1s[k];
            FMA4(z, hv, wv);
        }
        *(float4*)&buf[kk * 64 + 4 * Q] = z;
    }
    __syncthreads();
    if (t < 64) {
        float a = vf2;
        #pragma unroll
        for (int kk = 0; kk < 16; ++kk) a += buf[kk*64 + t];
        a2s[t] = fmaxf(a, 0.0f);
    }
    __syncthreads();

    // ---- FC3: 64 -> 32, relu. (kappa 16, Q 8) ----
    if (t < 128) {
        const int kk = t >> 3, Q = t & 7;
        const float* wp = F3T + 4 * Q;
        const int k0 = kk * 4;
        float4 z = {0.f, 0.f, 0.f, 0.f};
        #pragma unroll
        for (int k = k0; k < k0 + 4; ++k) {
            const float4 wv = *(const float4*)(wp + k * 32);
            const float hv = a2s[k];
            FMA4(z, hv, wv);
        }
        *(float4*)&buf[kk * 32 + 4 * Q] = z;
    }
    __syncthreads();
    if (t < 32) {
        float a = vf3;
        #pragma unroll
        for (int kk = 0; kk < 16; ++kk) a += buf[kk*32 + t];
        a3s[t] = fmaxf(a, 0.0f);
    }
    __syncthreads();

    // ---- FC4: 32 -> 3 ----
    if (t < 3) {
        const float4* wr = (const float4*)(f4w + t * 32);
        float a0 = f4b[t], a1 = 0.f;
        #pragma unroll
        for (int i = 0; i < 8; ++i) {
            const float4 wv = wr[i];
            const float4 hv = *(const float4*)&a3s[4 * i];
            a0 = fmaf(hv.x, wv.x, a0);
            a1 = fmaf(hv.y, wv.y, a1);
            a0 = fmaf(hv.z, wv.z, a0);
            a1 = fmaf(hv.w, wv.w, a1);
        }
        out[row * 3 + t] = a0 + a1;
    }
}

extern "C" void kernel_launch(void* const* d_in, const int* in_sizes, int n_in,
                              void* d_out, int out_size, void* d_ws, size_t ws_size,
                              hipStream_t stream) {
    const float* x   = (const float*)d_in[0];
    const float* w1i = (const float*)d_in[1];
    const float* b1  = (const float*)d_in[3];
    const float* w2i = (const float*)d_in[4];
    const float* b2  = (const float*)d_in[6];
    const float* w3i = (const float*)d_in[7];
    const float* b3  = (const float*)d_in[9];
    const float* w4i = (const float*)d_in[10];
    const float* b4  = (const float*)d_in[12];
    const float* f1w = (const float*)d_in[13];
    const float* f1b = (const float*)d_in[14];
    const float* f2w = (const float*)d_in[15];
    const float* f2b = (const float*)d_in[16];
    const float* f3w = (const float*)d_in[17];
    const float* f3b = (const float*)d_in[18];
    const float* f4w = (const float*)d_in[19];
    const float* f4b = (const float*)d_in[20];
    float* ws  = (float*)d_ws;
    float* out = (float*)d_out;

    prep_kernel<<<1084, 256, 0, stream>>>(w1i, w2i, w3i, w4i, b1, b2, b3, b4,
                                          f1w, f2w, f3w, ws);
    // 64 row-groups x 4 slices = 256 blocks (all co-resident on 256 CUs)
    lstm_fused_sliced<<<256, 512, 0, stream>>>(x, ws, f1b, f2b, f3b, f4w, f4b,
                                               out);
}

// Round 3
// 166.584 us; speedup vs baseline: 1.0740x; 1.0740x over previous
//
#include <hip/hip_runtime.h>
#include <math.h>

// ---------------------------------------------------------------------------
// Reference takes _lstm4(...)[0] -> only t=0 of the whole stack matters.
// With h0=c0=0 each layer is feed-forward: z = x0 @ Wih^T + b,
// c = sigmoid(i)*tanh(g) (f-gate multiplies c0=0 -> dropped),
// h = tanh(sigmoid(o)*tanh(c)).
//
// R6 = R3 structure (prep transpose + single fused kernel, block-local only;
// cross-block variants R4/R5 both regressed) with float4 output-quad
// ownership in every split-K phase: thread computes 4 adjacent outputs via
// one 16B weight load + FMA4 per k (k-major layout makes w[k*LD + 4Q]
// vectorizable). ~3x fewer load instructions in LSTM1/2 for the same bytes.
// ---------------------------------------------------------------------------

// ws layout (float offsets). Weights transposed to [K][3H], f-gate dropped,
// packed gate order: i | g | o.
#define O_W1T 0        // 87  x 768
#define O_W2T 66816    // 256 x 384
#define O_W3T 165120   // 128 x 192
#define O_W4T 189696   // 64  x 96
#define O_F1T 195840   // 32  x 128
#define O_F2T 199936   // 128 x 64
#define O_F3T 208128   // 64  x 32
#define O_B1  210176   // 768
#define O_B2  210944   // 384
#define O_B3  211328   // 192
#define O_B4  211520   // 96

__global__ __launch_bounds__(256) void prep_kernel(
    const float* __restrict__ w1i, const float* __restrict__ w2i,
    const float* __restrict__ w3i, const float* __restrict__ w4i,
    const float* __restrict__ b1,  const float* __restrict__ b2,
    const float* __restrict__ b3,  const float* __restrict__ b4,
    const float* __restrict__ f1w, const float* __restrict__ f2w,
    const float* __restrict__ f3w, float* __restrict__ ws)
{
    int i = blockIdx.x * 256 + threadIdx.x;
    if (i < 89088) {                                   // w1i [1024 x 87], H=256
        int row = i / 87, k = i - row * 87;
        int g = row >> 8;
        if (g != 1) {
            int base = (g == 0) ? 0 : (g == 2) ? 256 : 512;
            ws[O_W1T + k * 768 + base + (row & 255)] = w1i[i];
        }
    } else if (i < 220160) {                           // w2i [512 x 256], H=128
        int l = i - 89088;
        int row = l >> 8, k = l & 255;
        int g = row >> 7;
        if (g != 1) {
            int base = (g == 0) ? 0 : (g == 2) ? 128 : 256;
            ws[O_W2T + k * 384 + base + (row & 127)] = w2i[l];
        }
    } else if (i < 252928) {                           // w3i [256 x 128], H=64
        int l = i - 220160;
        int row = l >> 7, k = l & 127;
        int g = row >> 6;
        if (g != 1) {
            int base = (g == 0) ? 0 : (g == 2) ? 64 : 128;
            ws[O_W3T + k * 192 + base + (row & 63)] = w3i[l];
        }
    } else if (i < 261120) {                           // w4i [128 x 64], H=32
        int l = i - 252928;
        int row = l >> 6, k = l & 63;
        int g = row >> 5;
        if (g != 1) {
            int base = (g == 0) ? 0 : (g == 2) ? 32 : 64;
            ws[O_W4T + k * 96 + base + (row & 31)] = w4i[l];
        }
    } else if (i < 262144) {                           // b1 [1024]
        int l = i - 261120;
        int g = l >> 8;
        if (g != 1) {
            int base = (g == 0) ? 0 : (g == 2) ? 256 : 512;
            ws[O_B1 + base + (l & 255)] = b1[l];
        }
    } else if (i < 262656) {                           // b2 [512]
        int l = i - 262144;
        int g = l >> 7;
        if (g != 1) {
            int base = (g == 0) ? 0 : (g == 2) ? 128 : 256;
            ws[O_B2 + base + (l & 127)] = b2[l];
        }
    } else if (i < 262912) {                           // b3 [256]
        int l = i - 262656;
        int g = l >> 6;
        if (g != 1) {
            int base = (g == 0) ? 0 : (g == 2) ? 64 : 128;
            ws[O_B3 + base + (l & 63)] = b3[l];
        }
    } else if (i < 263040) {                           // b4 [128]
        int l = i - 262912;
        int g = l >> 5;
        if (g != 1) {
            int base = (g == 0) ? 0 : (g == 2) ? 32 : 64;
            ws[O_B4 + base + (l & 31)] = b4[l];
        }
    } else if (i < 267136) {                           // f1w [128 x 32]
        int l = i - 263040;
        int j = l >> 5, k = l & 31;
        ws[O_F1T + k * 128 + j] = f1w[l];
    } else if (i < 275328) {                           // f2w [64 x 128]
        int l = i - 267136;
        int j = l >> 7, k = l & 127;
        ws[O_F2T + k * 64 + j] = f2w[l];
    } else if (i < 277376) {                           // f3w [32 x 64]
        int l = i - 275328;
        int j = l >> 6, k = l & 63;
        ws[O_F3T + k * 32 + j] = f3w[l];
    }
}

__device__ __forceinline__ float frcp(float x) { return __builtin_amdgcn_rcpf(x); }
__device__ __forceinline__ float sigm(float x) { return frcp(1.0f + __expf(-x)); }
__device__ __forceinline__ float tanh_f(float x) { return 1.0f - 2.0f * frcp(1.0f + __expf(2.0f * x)); }
__device__ __forceinline__ float cell(float zi, float zg, float zo) {
    float c = sigm(zi) * tanh_f(zg);
    return tanh_f(sigm(zo) * tanh_f(c));
}

#define FMA4(z, xv, wv) \
    z.x = fmaf(xv, wv.x, z.x); z.y = fmaf(xv, wv.y, z.y); \
    z.z = fmaf(xv, wv.z, z.z); z.w = fmaf(xv, wv.w, z.w);

__global__ __launch_bounds__(512) void lstm_fused(
    const float* __restrict__ x, const float* __restrict__ ws,
    const float* __restrict__ f1b, const float* __restrict__ f2b,
    const float* __restrict__ f3b, const float* __restrict__ f4w,
    const float* __restrict__ f4b, float* __restrict__ out)
{
    const int t = threadIdx.x;
    const int r = blockIdx.x;                 // one batch row per block

    __shared__ float xs[87];
    __shared__ float h1[256], h2[128], h3[64], h4[32];
    __shared__ float a1[128], a2[64], a3[32];
    __shared__ __align__(16) float ps[1536];  // split-K partials, reused

    const float* W1T = ws + O_W1T;
    const float* W2T = ws + O_W2T;
    const float* W3T = ws + O_W3T;
    const float* W4T = ws + O_W4T;
    const float* F1T = ws + O_F1T;
    const float* F2T = ws + O_F2T;
    const float* F3T = ws + O_F3T;

    // bias preloads into registers (issue early, consumed after barriers)
    float b1i = 0.f, b1g = 0.f, b1o = 0.f;
    float b2i = 0.f, b2g = 0.f, b2o = 0.f, vf1 = 0.f;
    float b3i = 0.f, b3g = 0.f, b3o = 0.f, vf2 = 0.f;
    float b4i = 0.f, b4g = 0.f, b4o = 0.f, vf3 = 0.f;
    {
        const float* B1p = ws + O_B1;
        const float* B2p = ws + O_B2;
        const float* B3p = ws + O_B3;
        const float* B4p = ws + O_B4;
        if (t < 256) { b1i = B1p[t]; b1g = B1p[256 + t]; b1o = B1p[512 + t]; }
        if (t < 128) { b2i = B2p[t]; b2g = B2p[128 + t]; b2o = B2p[256 + t]; vf1 = f1b[t]; }
        if (t < 64)  { b3i = B3p[t]; b3g = B3p[64 + t];  b3o = B3p[128 + t]; vf2 = f2b[t]; }
        if (t < 32)  { b4i = B4p[t]; b4g = B4p[32 + t];  b4o = B4p[64 + t];  vf3 = f3b[t]; }
    }

    if (t < 87) xs[t] = x[r * 87 + t];
    __syncthreads();

    // ---- LSTM1: 87 -> 256. 192 output-quads x 2-way split-K (44/43) ----
    if (t < 384) {
        const int kp = t / 192, Q = t - kp * 192;
        const float* wp = W1T + 4 * Q;
        const int k0 = kp ? 44 : 0, k1 = kp ? 87 : 44;
        float4 z = {0.f, 0.f, 0.f, 0.f};
        #pragma unroll 8
        for (int k = k0; k < k1; ++k) {
            const float4 wv = *(const float4*)(wp + k * 768);
            FMA4(z, xs[k], wv);
        }
        *(float4*)&ps[kp * 768 + 4 * Q] = z;
    }
    __syncthreads();
    if (t < 256)
        h1[t] = cell(ps[t] + ps[768 + t] + b1i,
                     ps[256 + t] + ps[1024 + t] + b1g,
                     ps[512 + t] + ps[1280 + t] + b1o);
    __syncthreads();

    // ---- LSTM2: 256 -> 128. 96 quads x 4-way split-K ----
    if (t < 384) {
        const int kp = t / 96, Q = t - kp * 96;
        const float* wp = W2T + 4 * Q;
        const int k0 = kp * 64;
        float4 z = {0.f, 0.f, 0.f, 0.f};
        #pragma unroll 8
        for (int k = k0; k < k0 + 64; ++k) {
            const float4 wv = *(const float4*)(wp + k * 384);
            FMA4(z, h1[k], wv);
        }
        *(float4*)&ps[kp * 384 + 4 * Q] = z;
    }
    __syncthreads();
    if (t < 128) {
        float zi = b2i, zg = b2g, zo = b2o;
        #pragma unroll
        for (int kp = 0; kp < 4; ++kp) {
            zi += ps[kp * 384 + t];
            zg += ps[kp * 384 + 128 + t];
            zo += ps[kp * 384 + 256 + t];
        }
        h2[t] = cell(zi, zg, zo);
    }
    __syncthreads();

    // ---- LSTM3: 128 -> 64. 48 quads x 8-way split-K ----
    if (t < 384) {
        const int kp = t / 48, Q = t - kp * 48;
        const float* wp = W3T + 4 * Q;
        const int k0 = kp * 16;
        float4 z = {0.f, 0.f, 0.f, 0.f};
        #pragma unroll
        for (int k = k0; k < k0 + 16; ++k) {
            const float4 wv = *(const float4*)(wp + k * 192);
            FMA4(z, h2[k], wv);
        }
        *(float4*)&ps[kp * 192 + 4 * Q] = z;
    }
    __syncthreads();
    if (t < 64) {
        float zi = b3i, zg = b3g, zo = b3o;
        #pragma unroll
        for (int kp = 0; kp < 8; ++kp) {
            zi += ps[kp * 192 + t];
            zg += ps[kp * 192 + 64 + t];
            zo += ps[kp * 192 + 128 + t];
        }
        h3[t] = cell(zi, zg, zo);
    }
    __syncthreads();

    // ---- LSTM4: 64 -> 32. 24 quads x 16-way split-K ----
    if (t < 384) {
        const int kp = t / 24, Q = t - kp * 24;
        const float* wp = W4T + 4 * Q;
        const int k0 = kp * 4;
        float4 z = {0.f, 0.f, 0.f, 0.f};
        #pragma unroll
        for (int k = k0; k < k0 + 4; ++k) {
            const float4 wv = *(const float4*)(wp + k * 96);
            FMA4(z, h3[k], wv);
        }
        *(float4*)&ps[kp * 96 + 4 * Q] = z;
    }
    __syncthreads();
    if (t < 32) {
        float zi = b4i, zg = b4g, zo = b4o;
        #pragma unroll
        for (int kp = 0; kp < 16; ++kp) {
            zi += ps[kp * 96 + t];
            zg += ps[kp * 96 + 32 + t];
            zo += ps[kp * 96 + 64 + t];
        }
        h4[t] = cell(zi, zg, zo);
    }
    __syncthreads();

    // ---- FC1: 32 -> 128, relu. 32 quads x 8-way split-K ----
    if (t < 256) {
        const int kp = t >> 5, Q = t & 31;
        const float* wp = F1T + 4 * Q;
        const int k0 = kp * 4;
        float4 z = {0.f, 0.f, 0.f, 0.f};
        #pragma unroll
        for (int k = k0; k < k0 + 4; ++k) {
            const float4 wv = *(const float4*)(wp + k * 128);
            FMA4(z, h4[k], wv);
        }
        *(float4*)&ps[kp * 128 + 4 * Q] = z;
    }
    __syncthreads();
    if (t < 128) {
        float a = vf1;
        #pragma unroll
        for (int kp = 0; kp < 8; ++kp) a += ps[kp * 128 + t];
        a1[t] = fmaxf(a, 0.0f);
    }
    __syncthreads();

    // ---- FC2: 128 -> 64, relu. 16 quads x 16-way split-K ----
    if (t < 256) {
        const int kp = t >> 4, Q = t & 15;
        const float* wp = F2T + 4 * Q;
        const int k0 = kp * 8;
        float4 z = {0.f, 0.f, 0.f, 0.f};
        #pragma unroll
        for (int k = k0; k < k0 + 8; ++k) {
            const float4 wv = *(const float4*)(wp + k * 64);
            FMA4(z, a1[k], wv);
        }
        *(float4*)&ps[kp * 64 + 4 * Q] = z;
    }
    __syncthreads();
    if (t < 64) {
        float a = vf2;
        #pragma unroll
        for (int kp = 0; kp < 16; ++kp) a += ps[kp * 64 + t];
        a2[t] = fmaxf(a, 0.0f);
    }
    __syncthreads();

    // ---- FC3: 64 -> 32, relu. 8 quads x 16-way split-K ----
    if (t < 128) {
        const int kp = t >> 3, Q = t & 7;
        const float* wp = F3T + 4 * Q;
        const int k0 = kp * 4;
        float4 z = {0.f, 0.f, 0.f, 0.f};
        #pragma unroll
        for (int k = k0; k < k0 + 4; ++k) {
            const float4 wv = *(const float4*)(wp + k * 32);
            FMA4(z, a2[k], wv);
        }
        *(float4*)&ps[kp * 32 + 4 * Q] = z;
    }
    __syncthreads();
    if (t < 32) {
        float a = vf3;
        #pragma unroll
        for (int kp = 0; kp < 16; ++kp) a += ps[kp * 32 + t];
        a3[t] = fmaxf(a, 0.0f);
    }
    __syncthreads();

    // ---- FC4: 32 -> 3 ----
    if (t < 3) {
        const float4* wr = (const float4*)(f4w + t * 32);
        float a0 = f4b[t], a1v = 0.f;
        #pragma unroll
        for (int i = 0; i < 8; ++i) {
            const float4 wv = wr[i];
            const float4 hv = *(const float4*)&a3[4 * i];
            a0 = fmaf(hv.x, wv.x, a0);
            a1v = fmaf(hv.y, wv.y, a1v);
            a0 = fmaf(hv.z, wv.z, a0);
            a1v = fmaf(hv.w, wv.w, a1v);
        }
        out[r * 3 + t] = a0 + a1v;
    }
}

extern "C" void kernel_launch(void* const* d_in, const int* in_sizes, int n_in,
                              void* d_out, int out_size, void* d_ws, size_t ws_size,
                              hipStream_t stream) {
    const float* x   = (const float*)d_in[0];
    const float* w1i = (const float*)d_in[1];
    const float* b1  = (const float*)d_in[3];
    const float* w2i = (const float*)d_in[4];
    const float* b2  = (const float*)d_in[6];
    const float* w3i = (const float*)d_in[7];
    const float* b3  = (const float*)d_in[9];
    const float* w4i = (const float*)d_in[10];
    const float* b4  = (const float*)d_in[12];
    const float* f1w = (const float*)d_in[13];
    const float* f1b = (const float*)d_in[14];
    const float* f2w = (const float*)d_in[15];
    const float* f2b = (const float*)d_in[16];
    const float* f3w = (const float*)d_in[17];
    const float* f3b = (const float*)d_in[18];
    const float* f4w = (const float*)d_in[19];
    const float* f4b = (const float*)d_in[20];
    float* ws  = (float*)d_ws;
    float* out = (float*)d_out;

    prep_kernel<<<1084, 256, 0, stream>>>(w1i, w2i, w3i, w4i, b1, b2, b3, b4,
                                          f1w, f2w, f3w, ws);
    // one batch row per block (1 block/CU), 512 threads
    lstm_fused<<<256, 512, 0, stream>>>(x, ws, f1b, f2b, f3b, f4w, f4b, out);
}